// Round 2
// baseline (475.504 us; speedup 1.0000x reference)
//
#include <hip/hip_runtime.h>
#include <hip/hip_bf16.h>
#include <stdint.h>

// BraidCrossing: scale = mean(softmax(.), axis=-1) == 1/6 exactly (softmax sums to 1,
// mean over the 6-wide axis). => W1/b1/W2/b2/gelu chain is dead code.
// out_t = LN(LN(x_t + P_{t-1}/6) + P_{t+1}/6), P = x @ Wp^T + bp, one-sided at t=0, T-1.
// I/O is float32 (per harness spec); GEMM runs bf16 MFMA internally (f32 accum).

#define B_DIM 8
#define T_DIM 2048
#define D_DIM 2048
#define M_DIM (B_DIM * T_DIM)   // 16384
#define N_DIM D_DIM             // 2048
#define K_DIM D_DIM             // 2048

typedef __attribute__((ext_vector_type(8))) short short8;   // 8 bf16 in 4 VGPRs
typedef __attribute__((ext_vector_type(4))) float f32x4;

__device__ inline unsigned short f2bf(float f) {
    unsigned u = __float_as_uint(f);
    u += 0x7fffu + ((u >> 16) & 1u);   // RTNE
    return (unsigned short)(u >> 16);
}
__device__ inline float bf2f(unsigned u16) {
    return __uint_as_float(u16 << 16);
}
__device__ inline void unpack8(uint4 u, float* f) {
    f[0] = bf2f(u.x & 0xffffu); f[1] = bf2f(u.x >> 16);
    f[2] = bf2f(u.y & 0xffffu); f[3] = bf2f(u.y >> 16);
    f[4] = bf2f(u.z & 0xffffu); f[5] = bf2f(u.z >> 16);
    f[6] = bf2f(u.w & 0xffffu); f[7] = bf2f(u.w >> 16);
}

__device__ inline void async_ld16(const void* g, void* l) {
    __builtin_amdgcn_global_load_lds(
        (__attribute__((address_space(1))) void*)(g),
        (__attribute__((address_space(3))) void*)(l),
        16, 0, 0);
}

// ---------------- cast f32 -> bf16 ----------------
__global__ void cast_f32_bf16(const float* __restrict__ src,
                              unsigned short* __restrict__ dst, int n4) {
    int i = blockIdx.x * blockDim.x + threadIdx.x;
    if (i < n4) {
        float4 f = ((const float4*)src)[i];
        ushort4 o;
        o.x = f2bf(f.x); o.y = f2bf(f.y); o.z = f2bf(f.z); o.w = f2bf(f.w);
        ((ushort4*)dst)[i] = o;
    }
}

// ---------------- GEMM: P = Xb(MxK) @ Wb(NxK)^T + bp, bf16 in, bf16 out ----------------
// 128x128 tile, BK=32, 256 threads (4 waves), each wave 64x64 via 4x4 mfma 16x16x32.
__global__ void gemm_bt(const unsigned short* __restrict__ Xb,
                        const unsigned short* __restrict__ Wb,
                        const float* __restrict__ bp,
                        unsigned short* __restrict__ P)
{
    __shared__ unsigned short As[128 * 32];
    __shared__ unsigned short Bs[128 * 32];

    const int tid  = threadIdx.x;
    const int lane = tid & 63;
    const int wave = tid >> 6;
    const int m0 = blockIdx.y * 128;
    const int n0 = blockIdx.x * 128;

    // staging map: LDS byte offset == wave-uniform + lane*16 (global_load_lds requirement)
    const int srow = tid >> 2;           // 0..63
    const int scol = (tid & 3) * 8;      // 0,8,16,24

    // compute map
    const int rw = (wave >> 1) * 64;
    const int cw = (wave & 1) * 64;
    const int fr = lane & 15;            // fragment m (A) / n (B)
    const int fk = (lane >> 4) * 8;      // fragment k base

    f32x4 acc[4][4];
#pragma unroll
    for (int i = 0; i < 4; i++)
#pragma unroll
        for (int j = 0; j < 4; j++) acc[i][j] = (f32x4){0.f, 0.f, 0.f, 0.f};

    for (int k0 = 0; k0 < K_DIM; k0 += 32) {
#pragma unroll
        for (int q = 0; q < 2; q++) {
            int row = q * 64 + srow;
            async_ld16(Xb + (size_t)(m0 + row) * K_DIM + k0 + scol, As + row * 32 + scol);
            async_ld16(Wb + (size_t)(n0 + row) * K_DIM + k0 + scol, Bs + row * 32 + scol);
        }
        __syncthreads();

        short8 a[4], b[4];
#pragma unroll
        for (int i = 0; i < 4; i++)
            a[i] = *(const short8*)(As + (rw + 16 * i + fr) * 32 + fk);
#pragma unroll
        for (int j = 0; j < 4; j++)
            b[j] = *(const short8*)(Bs + (cw + 16 * j + fr) * 32 + fk);

#pragma unroll
        for (int i = 0; i < 4; i++)
#pragma unroll
            for (int j = 0; j < 4; j++)
                acc[i][j] = __builtin_amdgcn_mfma_f32_16x16x32_bf16(a[i], b[j], acc[i][j], 0, 0, 0);
        __syncthreads();
    }

    // epilogue: C/D layout col=lane&15, row=(lane>>4)*4+reg  [m89/m91-verified]
    const int crow = (lane >> 4) * 4;
    const int ccol = lane & 15;
#pragma unroll
    for (int j = 0; j < 4; j++) {
        int col = n0 + cw + 16 * j + ccol;
        float bpv = bp[col];
#pragma unroll
        for (int i = 0; i < 4; i++) {
            size_t base = (size_t)(m0 + rw + 16 * i + crow) * N_DIM + col;
#pragma unroll
            for (int r = 0; r < 4; r++)
                P[base + (size_t)r * N_DIM] = f2bf(acc[i][j][r] + bpv);
        }
    }
}

// ---------------- fused double-LayerNorm ----------------
__device__ inline void ln_stage(float* v, const float* g, const float* be, float* sm, int tid) {
    float s = 0.f, q = 0.f;
#pragma unroll
    for (int i = 0; i < 8; i++) { s += v[i]; q += v[i] * v[i]; }
#pragma unroll
    for (int off = 32; off; off >>= 1) { s += __shfl_down(s, off); q += __shfl_down(q, off); }
    int w = tid >> 6;
    if ((tid & 63) == 0) { sm[w * 2] = s; sm[w * 2 + 1] = q; }
    __syncthreads();
    s = sm[0] + sm[2] + sm[4] + sm[6];
    q = sm[1] + sm[3] + sm[5] + sm[7];
    __syncthreads();
    const float invD = 1.0f / (float)D_DIM;
    float mu = s * invD;
    float var = q * invD - mu * mu;
    float rs = rsqrtf(var + 1e-5f);
#pragma unroll
    for (int i = 0; i < 8; i++) v[i] = (v[i] - mu) * rs * g[i] + be[i];
}

__global__ void ln_kernel(const float* __restrict__ x,
                          const unsigned short* __restrict__ P,
                          const float* __restrict__ gamma,
                          const float* __restrict__ beta,
                          float* __restrict__ out)
{
    const int r = blockIdx.x;          // 0..M-1, row = b*T + t
    const int t = r & (T_DIM - 1);
    const int tid = threadIdx.x;       // 256 threads, 8 elems each
    __shared__ float sm[8];

    float v[8], g[8], be[8];
    {
        const float4* xr = (const float4*)(x + (size_t)r * D_DIM);
        float4 v0 = xr[2 * tid], v1 = xr[2 * tid + 1];
        v[0] = v0.x; v[1] = v0.y; v[2] = v0.z; v[3] = v0.w;
        v[4] = v1.x; v[5] = v1.y; v[6] = v1.z; v[7] = v1.w;
        float4 g0 = ((const float4*)gamma)[2 * tid], g1 = ((const float4*)gamma)[2 * tid + 1];
        g[0] = g0.x; g[1] = g0.y; g[2] = g0.z; g[3] = g0.w;
        g[4] = g1.x; g[5] = g1.y; g[6] = g1.z; g[7] = g1.w;
        float4 b0 = ((const float4*)beta)[2 * tid], b1 = ((const float4*)beta)[2 * tid + 1];
        be[0] = b0.x; be[1] = b0.y; be[2] = b0.z; be[3] = b0.w;
        be[4] = b1.x; be[5] = b1.y; be[6] = b1.z; be[7] = b1.w;
    }

    const float inv6 = 1.0f / 6.0f;

    if (t > 0) {  // tmp_t = LN(x_t + P_{t-1}/6)
        float p[8];
        unpack8(((const uint4*)(P + (size_t)(r - 1) * D_DIM))[tid], p);
#pragma unroll
        for (int i = 0; i < 8; i++) v[i] += p[i] * inv6;
        ln_stage(v, g, be, sm, tid);
    }
    if (t < T_DIM - 1) {  // out_t = LN(tmp_t + P_{t+1}/6)
        float p[8];
        unpack8(((const uint4*)(P + (size_t)(r + 1) * D_DIM))[tid], p);
#pragma unroll
        for (int i = 0; i < 8; i++) v[i] += p[i] * inv6;
        ln_stage(v, g, be, sm, tid);
    }

    float4* orow = (float4*)(out + (size_t)r * D_DIM);
    orow[2 * tid]     = (float4){v[0], v[1], v[2], v[3]};
    orow[2 * tid + 1] = (float4){v[4], v[5], v[6], v[7]};
}

extern "C" void kernel_launch(void* const* d_in, const int* in_sizes, int n_in,
                              void* d_out, int out_size, void* d_ws, size_t ws_size,
                              hipStream_t stream) {
    // inputs (setup_inputs order): x, W1, b1, W2, b2, Wp, bp, gamma, beta — W1/b1/W2/b2 dead.
    const float* x     = (const float*)d_in[0];
    const float* Wp    = (const float*)d_in[5];
    const float* bp    = (const float*)d_in[6];
    const float* gamma = (const float*)d_in[7];
    const float* beta  = (const float*)d_in[8];
    float* out = (float*)d_out;

    // workspace layout (bytes): Xb bf16 [64 MiB] | Wb bf16 [8 MiB] | P bf16 [64 MiB]
    unsigned short* Xb = (unsigned short*)d_ws;
    unsigned short* Wb = Xb + (size_t)M_DIM * K_DIM;
    unsigned short* P  = Wb + (size_t)N_DIM * K_DIM;

    const int nx4 = (M_DIM * K_DIM) / 4;   // 8388608
    const int nw4 = (N_DIM * K_DIM) / 4;   // 1048576
    cast_f32_bf16<<<nx4 / 256, 256, 0, stream>>>(x, Xb, nx4);
    cast_f32_bf16<<<nw4 / 256, 256, 0, stream>>>(Wp, Wb, nw4);

    dim3 ggrid(N_DIM / 128, M_DIM / 128);  // (16, 128)
    gemm_bt<<<ggrid, 256, 0, stream>>>(Xb, Wb, bp, P);
    ln_kernel<<<M_DIM, 256, 0, stream>>>(x, P, gamma, beta, out);
}

// Round 3
// 420.059 us; speedup vs baseline: 1.1320x; 1.1320x over previous
//
#include <hip/hip_runtime.h>
#include <hip/hip_bf16.h>
#include <stdint.h>

// BraidCrossing: scale = mean(softmax(.), axis=-1) == 1/6 exactly (softmax sums to 1,
// mean over the 6-wide axis) => W1/b1/W2/b2/gelu chain is dead code.
// out_t = LN(LN(x_t + P_{t-1}/6) + P_{t+1}/6), P = x @ Wp^T + bp, one-sided at t=0, T-1.
// I/O float32; GEMM runs bf16 MFMA (f32 accum). R3: BK=64 + XOR-swizzled LDS to kill
// the 8-way bank conflicts (1.68e7 in R2), halved barrier count; LN reads bf16 Xb.

#define B_DIM 8
#define T_DIM 2048
#define D_DIM 2048
#define M_DIM (B_DIM * T_DIM)   // 16384
#define N_DIM D_DIM             // 2048
#define K_DIM D_DIM             // 2048

typedef __attribute__((ext_vector_type(8))) short short8;   // 8 bf16 in 4 VGPRs
typedef __attribute__((ext_vector_type(4))) float f32x4;

__device__ inline unsigned short f2bf(float f) {
    unsigned u = __float_as_uint(f);
    u += 0x7fffu + ((u >> 16) & 1u);   // RTNE
    return (unsigned short)(u >> 16);
}
__device__ inline float bf2f(unsigned u16) {
    return __uint_as_float(u16 << 16);
}
__device__ inline void unpack8(uint4 u, float* f) {
    f[0] = bf2f(u.x & 0xffffu); f[1] = bf2f(u.x >> 16);
    f[2] = bf2f(u.y & 0xffffu); f[3] = bf2f(u.y >> 16);
    f[4] = bf2f(u.z & 0xffffu); f[5] = bf2f(u.z >> 16);
    f[6] = bf2f(u.w & 0xffffu); f[7] = bf2f(u.w >> 16);
}

__device__ inline void async_ld16(const void* g, void* l) {
    __builtin_amdgcn_global_load_lds(
        (__attribute__((address_space(1))) void*)(g),
        (__attribute__((address_space(3))) void*)(l),
        16, 0, 0);
}

// ---------------- cast f32 -> bf16 (x and Wp in one launch) ----------------
__global__ void cast_f32_bf16(const float* __restrict__ x, unsigned short* __restrict__ Xb,
                              const float* __restrict__ Wp, unsigned short* __restrict__ Wb,
                              int nx4, int ntot4) {
    int i = blockIdx.x * blockDim.x + threadIdx.x;
    if (i >= ntot4) return;
    const float* src; unsigned short* dst; int j;
    if (i < nx4) { src = x; dst = Xb; j = i; }
    else         { src = Wp; dst = Wb; j = i - nx4; }
    float4 f = ((const float4*)src)[j];
    ushort4 o;
    o.x = f2bf(f.x); o.y = f2bf(f.y); o.z = f2bf(f.z); o.w = f2bf(f.w);
    ((ushort4*)dst)[j] = o;
}

// ---------------- GEMM: P = Xb(MxK) @ Wb(NxK)^T + bp, bf16 in, bf16 out ----------------
// 128x128 tile, BK=64, 256 threads (4 waves), each wave 64x64 via 4x4 mfma 16x16x32.
// LDS layout: row-major 128B rows, 16B chunks XOR-swizzled: phys = logical ^ (row&7).
__global__ void gemm_bt(const unsigned short* __restrict__ Xb,
                        const unsigned short* __restrict__ Wb,
                        const float* __restrict__ bp,
                        unsigned short* __restrict__ P)
{
    __shared__ unsigned short As[128 * 64];   // 16 KB
    __shared__ unsigned short Bs[128 * 64];   // 16 KB

    const int tid  = threadIdx.x;
    const int lane = tid & 63;
    const int wave = tid >> 6;
    const int m0 = blockIdx.y * 128;
    const int n0 = blockIdx.x * 128;

    // compute map
    const int rw = (wave >> 1) * 64;
    const int cw = (wave & 1) * 64;
    const int fr = lane & 15;            // fragment m (A) / n (B)
    const int lq = lane >> 4;            // 0..3 -> logical k-chunk within half

    // staging: instr (wave, q): chunk index ci = (wave*4+q)*64 + lane; 16B chunks,
    // row = ci>>3 (8 chunks/row), phys col = ci&7, logical col = phys ^ (row&7).
    int s_r[4], s_l[4], s_ci[4];
#pragma unroll
    for (int q = 0; q < 4; q++) {
        int ci = (wave * 4 + q) * 64 + lane;
        s_ci[q] = ci;
        s_r[q] = ci >> 3;
        s_l[q] = (ci & 7) ^ (s_r[q] & 7);
    }

    f32x4 acc[4][4];
#pragma unroll
    for (int i = 0; i < 4; i++)
#pragma unroll
        for (int j = 0; j < 4; j++) acc[i][j] = (f32x4){0.f, 0.f, 0.f, 0.f};

    for (int k0 = 0; k0 < K_DIM; k0 += 64) {
#pragma unroll
        for (int q = 0; q < 4; q++) {
            async_ld16(Xb + (size_t)(m0 + s_r[q]) * K_DIM + k0 + s_l[q] * 8,
                       As + s_ci[q] * 8);
            async_ld16(Wb + (size_t)(n0 + s_r[q]) * K_DIM + k0 + s_l[q] * 8,
                       Bs + s_ci[q] * 8);
        }
        __syncthreads();

#pragma unroll
        for (int kk = 0; kk < 2; kk++) {          // two 32-wide k sub-steps
            const int l = kk * 4 + lq;            // logical chunk 0..7
            short8 a[4], b[4];
#pragma unroll
            for (int i = 0; i < 4; i++) {
                int row = rw + 16 * i + fr;
                a[i] = *(const short8*)(As + row * 64 + (l ^ (row & 7)) * 8);
            }
#pragma unroll
            for (int j = 0; j < 4; j++) {
                int row = cw + 16 * j + fr;
                b[j] = *(const short8*)(Bs + row * 64 + (l ^ (row & 7)) * 8);
            }
#pragma unroll
            for (int i = 0; i < 4; i++)
#pragma unroll
                for (int j = 0; j < 4; j++)
                    acc[i][j] = __builtin_amdgcn_mfma_f32_16x16x32_bf16(a[i], b[j], acc[i][j], 0, 0, 0);
        }
        __syncthreads();
    }

    // epilogue: C/D layout col=lane&15, row=(lane>>4)*4+reg  [m89/m91-verified]
    const int crow = (lane >> 4) * 4;
    const int ccol = lane & 15;
#pragma unroll
    for (int j = 0; j < 4; j++) {
        int col = n0 + cw + 16 * j + ccol;
        float bpv = bp[col];
#pragma unroll
        for (int i = 0; i < 4; i++) {
            size_t base = (size_t)(m0 + rw + 16 * i + crow) * N_DIM + col;
#pragma unroll
            for (int r = 0; r < 4; r++)
                P[base + (size_t)r * N_DIM] = f2bf(acc[i][j][r] + bpv);
        }
    }
}

// ---------------- fused double-LayerNorm ----------------
__device__ inline void ln_stage(float* v, const float* g, const float* be, float* sm, int tid) {
    float s = 0.f, q = 0.f;
#pragma unroll
    for (int i = 0; i < 8; i++) { s += v[i]; q += v[i] * v[i]; }
#pragma unroll
    for (int off = 32; off; off >>= 1) { s += __shfl_down(s, off); q += __shfl_down(q, off); }
    int w = tid >> 6;
    if ((tid & 63) == 0) { sm[w * 2] = s; sm[w * 2 + 1] = q; }
    __syncthreads();
    s = sm[0] + sm[2] + sm[4] + sm[6];
    q = sm[1] + sm[3] + sm[5] + sm[7];
    __syncthreads();
    const float invD = 1.0f / (float)D_DIM;
    float mu = s * invD;
    float var = q * invD - mu * mu;
    float rs = rsqrtf(var + 1e-5f);
#pragma unroll
    for (int i = 0; i < 8; i++) v[i] = (v[i] - mu) * rs * g[i] + be[i];
}

__global__ void ln_kernel(const unsigned short* __restrict__ Xb,
                          const unsigned short* __restrict__ P,
                          const float* __restrict__ gamma,
                          const float* __restrict__ beta,
                          float* __restrict__ out)
{
    const int r = blockIdx.x;          // 0..M-1, row = b*T + t
    const int t = r & (T_DIM - 1);
    const int tid = threadIdx.x;       // 256 threads, 8 elems each
    __shared__ float sm[8];

    float v[8], g[8], be[8];
    unpack8(((const uint4*)(Xb + (size_t)r * D_DIM))[tid], v);
    {
        float4 g0 = ((const float4*)gamma)[2 * tid], g1 = ((const float4*)gamma)[2 * tid + 1];
        g[0] = g0.x; g[1] = g0.y; g[2] = g0.z; g[3] = g0.w;
        g[4] = g1.x; g[5] = g1.y; g[6] = g1.z; g[7] = g1.w;
        float4 b0 = ((const float4*)beta)[2 * tid], b1 = ((const float4*)beta)[2 * tid + 1];
        be[0] = b0.x; be[1] = b0.y; be[2] = b0.z; be[3] = b0.w;
        be[4] = b1.x; be[5] = b1.y; be[6] = b1.z; be[7] = b1.w;
    }

    const float inv6 = 1.0f / 6.0f;

    if (t > 0) {  // tmp_t = LN(x_t + P_{t-1}/6)
        float p[8];
        unpack8(((const uint4*)(P + (size_t)(r - 1) * D_DIM))[tid], p);
#pragma unroll
        for (int i = 0; i < 8; i++) v[i] += p[i] * inv6;
        ln_stage(v, g, be, sm, tid);
    }
    if (t < T_DIM - 1) {  // out_t = LN(tmp_t + P_{t+1}/6)
        float p[8];
        unpack8(((const uint4*)(P + (size_t)(r + 1) * D_DIM))[tid], p);
#pragma unroll
        for (int i = 0; i < 8; i++) v[i] += p[i] * inv6;
        ln_stage(v, g, be, sm, tid);
    }

    float4* orow = (float4*)(out + (size_t)r * D_DIM);
    orow[2 * tid]     = (float4){v[0], v[1], v[2], v[3]};
    orow[2 * tid + 1] = (float4){v[4], v[5], v[6], v[7]};
}

extern "C" void kernel_launch(void* const* d_in, const int* in_sizes, int n_in,
                              void* d_out, int out_size, void* d_ws, size_t ws_size,
                              hipStream_t stream) {
    // inputs (setup_inputs order): x, W1, b1, W2, b2, Wp, bp, gamma, beta — W1/b1/W2/b2 dead.
    const float* x     = (const float*)d_in[0];
    const float* Wp    = (const float*)d_in[5];
    const float* bp    = (const float*)d_in[6];
    const float* gamma = (const float*)d_in[7];
    const float* beta  = (const float*)d_in[8];
    float* out = (float*)d_out;

    // workspace layout: Xb bf16 [64 MiB] | Wb bf16 [8 MiB] | P bf16 [64 MiB]
    unsigned short* Xb = (unsigned short*)d_ws;
    unsigned short* Wb = Xb + (size_t)M_DIM * K_DIM;
    unsigned short* P  = Wb + (size_t)N_DIM * K_DIM;

    const int nx4   = (M_DIM * K_DIM) / 4;            // 8388608
    const int ntot4 = nx4 + (N_DIM * K_DIM) / 4;      // + 1048576
    cast_f32_bf16<<<(ntot4 + 255) / 256, 256, 0, stream>>>(x, Xb, Wp, Wb, nx4, ntot4);

    dim3 ggrid(N_DIM / 128, M_DIM / 128);  // (16, 128)
    gemm_bt<<<ggrid, 256, 0, stream>>>(Xb, Wb, bp, P);
    ln_kernel<<<M_DIM, 256, 0, stream>>>(Xb, P, gamma, beta, out);
}